// Round 7
// baseline (427.181 us; speedup 1.0000x reference)
//
#include <hip/hip_runtime.h>
#include <hip/hip_bf16.h>

// B=4, N=2048, DIMX=384, DIMQ=48, H=8.
// out_b = sum_h softmax(Q K^T/sqrt(48)) @ U_bh,  U_bh = X_b M_h^T,  M_h = W_rh W_vh.
// ws layout (bytes), with Xw/Wqw/Wkw aliased INSIDE Ow (dead until attn runs):
//   Mw  bf16 [h*384+c][k:384]          @ 0           (2,359,296)
//   Qw  bf16 [bh][i:2048][d:64 pad]    @ 2,359,296   (8,388,608)
//   Kw  bf16 same                      @ 10,747,904  (8,388,608)
//   UT  bf16 [bh][jt:32][c:384][j:64]  @ 19,136,512  (50,331,648)   (tiled, round 10)
//   Ow  bf16 [bh][i:2048][c:384]       @ 69,468,160  (50,331,648)
//     Xw  bf16 [b][j:2048][k:384]      @ 69,468,160  (6,291,456)   } alias Ow
//     Wqw bf16 [384][384]              @ 75,759,616  (294,912)     }
//     Wkw bf16 [384][384]              @ 76,054,528  (294,912)     }
// peak = 119,799,808 B
//
// ROUND-11 CHANGE: barrier amortization, register-safe. Two 64-j subtiles per
// barrier (16 barriers instead of 32). Unlike R5 (which held ufA+ufB across the
// barrier: +96 VGPR -> 1GB scratch), ufB is loaded INSIDE the PV(A) tc-loop,
// each ufB[tc] issued as ufA[tc] dies -> live U stays 48 VGPR (pattern register-
// verified in R1 at 128 VGPR). K prefetch reloads kfA/kfB in place (no kn temps).
// Peak live ~= R0's proven 128 arch + 96 acc. Plus exp2f -> raw v_exp_f32
// builtin (drops OCML range-handling from the serial softmax chain).

typedef short bf16x8 __attribute__((ext_vector_type(8)));
typedef float f32x4 __attribute__((ext_vector_type(4)));
typedef unsigned short ushort_t;
typedef unsigned int uint_t;

#define MFMA16(A, B, C) __builtin_amdgcn_mfma_f32_16x16x32_bf16(A, B, C, 0, 0, 0)

__device__ __forceinline__ ushort_t bits_bf16(float a) {
  __hip_bfloat16 h = __float2bfloat16(a);
  return *reinterpret_cast<ushort_t*>(&h);
}

// ---------- fp32 -> bf16 convert ----------
__global__ __launch_bounds__(256) void cvt_kernel(const float* __restrict__ src,
                                                  ushort_t* __restrict__ dst, int n4) {
  const int idx = blockIdx.x * 256 + threadIdx.x;
  if (idx >= n4) return;
  const float4 v = ((const float4*)src)[idx];
  ushort4 o;
  o.x = bits_bf16(v.x); o.y = bits_bf16(v.y); o.z = bits_bf16(v.z); o.w = bits_bf16(v.w);
  ((ushort4*)dst)[idx] = o;
}

// ---------- M_h = W_rh * W_vh  (fp32 compute, bf16 out; tiny) ----------
__global__ __launch_bounds__(256) void prep_m_kernel(const float* __restrict__ Wr,
                                                     const float* __restrict__ Wv,
                                                     ushort_t* __restrict__ Mw) {
  __shared__ float As[32][68];
  __shared__ float Bs[32][68];
  const int t = threadIdx.x;
  const int d0 = blockIdx.x << 6;
  const int k0 = blockIdx.y << 6;
  const int h  = blockIdx.z;
  const int ty = t >> 4, tx = t & 15;
  float acc[4][4] = {};
  for (int x0 = 0; x0 < 384; x0 += 32) {
#pragma unroll
    for (int rep = 0; rep < 2; ++rep) {
      int idx = t + (rep << 8);
      int row = idx >> 3, kq = (idx & 7) << 2;
      const float4 a = *(const float4*)&Wr[(size_t)(d0 + row) * 3072 + h * 384 + x0 + kq];
      As[kq + 0][row] = a.x; As[kq + 1][row] = a.y; As[kq + 2][row] = a.z; As[kq + 3][row] = a.w;
      int bro = idx >> 4, bc4 = (idx & 15) << 2;
      *(float4*)&Bs[bro][bc4] = *(const float4*)&Wv[(size_t)(h * 384 + x0 + bro) * 384 + k0 + bc4];
    }
    __syncthreads();
#pragma unroll
    for (int kk = 0; kk < 32; ++kk) {
      const float4 av = *(const float4*)&As[kk][ty << 2];
      const float4 bv = *(const float4*)&Bs[kk][tx << 2];
      const float a[4] = {av.x, av.y, av.z, av.w};
      const float b[4] = {bv.x, bv.y, bv.z, bv.w};
#pragma unroll
      for (int r = 0; r < 4; ++r)
#pragma unroll
        for (int c = 0; c < 4; ++c) acc[r][c] = fmaf(a[r], b[c], acc[r][c]);
    }
    __syncthreads();
  }
#pragma unroll
  for (int r = 0; r < 4; ++r)
#pragma unroll
    for (int c = 0; c < 4; ++c)
      Mw[(size_t)(h * 384 + d0 + (ty << 2) + r) * 384 + k0 + (tx << 2) + c] =
          bits_bf16(acc[r][c]);
}

// ---------- unified bf16 MFMA GEMM ----------
// MODE 0: dst = Q/K packed [bh][i][64-pad]. MODE 1: dst = UT TILED [bh][jt][c][64].
template <int MODE>
__global__ __launch_bounds__(256) void gemm_kernel(const ushort_t* __restrict__ Aall,
                                                   const ushort_t* __restrict__ Ball,
                                                   ushort_t* __restrict__ dst) {
  __shared__ ushort_t As[128 * 40];
  __shared__ ushort_t Bs[128 * 40];
  const int t = threadIdx.x;
  const int w = t >> 6, lane = t & 63, quad = lane >> 4, l16 = lane & 15;
  const int m0 = blockIdx.x << 7;
  const int n0 = blockIdx.y << 7;
  const ushort_t* Ap;
  const ushort_t* Bp;
  if (MODE == 0) {
    Ap = Aall; Bp = Ball;
  } else {
    const int bh = blockIdx.z, h = bh & 7, b = bh >> 3;
    Ap = Aall + (size_t)h * 384 * 384;
    Bp = Ball + (size_t)b * 2048 * 384;
  }
  const int wm = (w & 1) << 6, wn = (w >> 1) << 6;
  f32x4 acc[4][4] = {};

  for (int k0 = 0; k0 < 384; k0 += 32) {
    __syncthreads();
#pragma unroll
    for (int rep = 0; rep < 2; ++rep) {
      const int idx = t + (rep << 8);
      const int row = idx >> 2, c8 = (idx & 3) << 3;
      *(bf16x8*)&As[row * 40 + c8] = *(const bf16x8*)&Ap[(size_t)(m0 + row) * 384 + k0 + c8];
      *(bf16x8*)&Bs[row * 40 + c8] = *(const bf16x8*)&Bp[(size_t)(n0 + row) * 384 + k0 + c8];
    }
    __syncthreads();
    bf16x8 af[4], bfr[4];
#pragma unroll
    for (int x = 0; x < 4; ++x) {
      af[x] = *(const bf16x8*)&As[(wm + x * 16 + l16) * 40 + quad * 8];
      bfr[x] = *(const bf16x8*)&Bs[(wn + x * 16 + l16) * 40 + quad * 8];
    }
#pragma unroll
    for (int ti = 0; ti < 4; ++ti)
#pragma unroll
      for (int tj = 0; tj < 4; ++tj)
        acc[ti][tj] = MFMA16(af[ti], bfr[tj], acc[ti][tj]);
  }

#pragma unroll
  for (int ti = 0; ti < 4; ++ti) {
    const int gm0 = m0 + wm + ti * 16 + quad * 4;
#pragma unroll
    for (int tj = 0; tj < 4; ++tj) {
      const int gn = n0 + wn + tj * 16 + l16;
#pragma unroll
      for (int r = 0; r < 4; ++r) {
        const ushort_t v = bits_bf16(acc[ti][tj][r]);
        if (MODE == 0) {
          const int m = gm0 + r, b = m >> 11, i = m & 2047;
          const int h = gn / 48, dd = gn - h * 48;
          dst[(size_t)(((b << 3) + h) * 2048 + i) * 64 + dd] = v;
        } else {
          // TILED UT store: [bh][jt=gn>>6][c=gm0+r][jo=gn&63]
          const int jt = gn >> 6, jo = gn & 63;
          dst[(size_t)blockIdx.z * 786432 + (size_t)jt * 24576 +
              (size_t)(gm0 + r) * 64 + jo] = v;
        }
      }
    }
  }
}

// ---------- fused attention via MFMA: 128-j per barrier, staggered U reload ----------
__global__ __launch_bounds__(256, 2) void attn_pv_kernel(const ushort_t* __restrict__ Qw,
                                                         const ushort_t* __restrict__ Kw,
                                                         const ushort_t* __restrict__ UT,
                                                         __hip_bfloat16* __restrict__ Ow) {
  __shared__ uint_t Ps[2][2][64 * 44];   // [buf][subtile] : 45,056 B
  __shared__ float Lw[4][64];
  __shared__ float Ls[64];

  const int t = threadIdx.x;
  const int w = t >> 6, lane = t & 63, quad = lane >> 4, l16 = lane & 15;
  const int bid = blockIdx.x;
  const int h = bid & 7, i0 = ((bid >> 3) & 31) << 6, b = bid >> 8;
  const int bh = (b << 3) + h;

  const ushort_t* Qg = Qw + ((size_t)bh * 2048 + i0 + l16) * 64 + quad * 8;
  const ushort_t* Kg = Kw + ((size_t)bh * 2048 + w * 16 + l16) * 64 + quad * 8;
  // Tiled U: up(jt64, tc) = Ug + jt64*24576 + tc*1024  (fully contiguous 1KB/load)
  const ushort_t* Ug = UT + (size_t)bh * 786432 + (size_t)(w * 96 + l16) * 64 + quad * 8;

  bf16x8 qf[4][2];
#pragma unroll
  for (int ti = 0; ti < 4; ++ti)
#pragma unroll
    for (int kh = 0; kh < 2; ++kh)
      qf[ti][kh] = *(const bf16x8*)(Qg + (size_t)ti * 16 * 64 + kh * 32);

  f32x4 acc[4][6] = {};
  float lp[4] = {0.f, 0.f, 0.f, 0.f};
  // exp(s/sqrt(48)) = exp2(s * log2(e)/sqrt(48)); raw v_exp_f32 (inputs far in-range)
  const float c_exp = 0.14433756729740643f * 1.4426950408889634f;

  // prologue: K fragments for subtiles 0 (A) and 1 (B); K tile T at byte-row T*4096
  bf16x8 kfA0 = *(const bf16x8*)(Kg);
  bf16x8 kfA1 = *(const bf16x8*)(Kg + 32);
  bf16x8 kfB0 = *(const bf16x8*)(Kg + 4096);
  bf16x8 kfB1 = *(const bf16x8*)(Kg + 4096 + 32);

#define LGKM_BARRIER()                                                                 \
  __builtin_amdgcn_sched_barrier(0);                                                   \
  asm volatile("s_waitcnt lgkmcnt(0)");                                                \
  __builtin_amdgcn_s_barrier();                                                        \
  __builtin_amdgcn_sched_barrier(0);

  // scores+exp+pack for one 64-j subtile: K frags (KF0,KF1) -> PW; lp from stored bits
#define SM_PHASE(PW, KF0, KF1)                                                         \
  _Pragma("unroll") for (int ti = 0; ti < 4; ++ti) {                                   \
    f32x4 z = {0.f, 0.f, 0.f, 0.f};                                                    \
    z = MFMA16(KF0, qf[ti][0], z);                                                     \
    z = MFMA16(KF1, qf[ti][1], z);                                                     \
    const uint_t r0 = __float_as_uint(__builtin_amdgcn_exp2f(z[0] * c_exp)) + 0x8000u; \
    const uint_t r1 = __float_as_uint(__builtin_amdgcn_exp2f(z[1] * c_exp)) + 0x8000u; \
    const uint_t r2 = __float_as_uint(__builtin_amdgcn_exp2f(z[2] * c_exp)) + 0x8000u; \
    const uint_t r3 = __float_as_uint(__builtin_amdgcn_exp2f(z[3] * c_exp)) + 0x8000u; \
    const uint_t p0 = __builtin_amdgcn_perm(r1, r0, 0x07060302u);                      \
    const uint_t p1 = __builtin_amdgcn_perm(r3, r2, 0x07060302u);                      \
    PW[ti][0] = p0;                                                                    \
    PW[ti][1] = p1;                                                                    \
    lp[ti] += (__uint_as_float(p0 << 16) + __uint_as_float(p0 & 0xffff0000u)) +        \
              (__uint_as_float(p1 << 16) + __uint_as_float(p1 & 0xffff0000u));         \
  }

#define PS_WRITE(CUR, SUB, PW)                                                         \
  {                                                                                    \
    uint2* p = (uint2*)&Ps[CUR][SUB][w * 8 + quad * 2];                                \
    _Pragma("unroll") for (int ti = 0; ti < 4; ++ti)                                   \
        *(uint2*)((uint_t*)p + (ti * 16 + l16) * 44) = uint2{PW[ti][0], PW[ti][1]};    \
  }

#define PA_READ(PA, CUR, SUB)                                                          \
  _Pragma("unroll") for (int ti = 0; ti < 4; ++ti)                                     \
      _Pragma("unroll") for (int ks = 0; ks < 2; ++ks)                                 \
          PA[ti][ks] =                                                                 \
              *(const bf16x8*)&Ps[CUR][SUB][(ti * 16 + l16) * 44 + ks * 16 + quad * 4];

  // one iteration: 128 j's (subtiles tA=2*JTP, tB=tA+1), ONE barrier.
#define ATTN_STEP(JTP, CUR)                                                            \
  {                                                                                    \
    const int tA = (JTP) << 1, tB = tA + 1;                                            \
    const int tA2 = (tA + 2) & 31, tB2 = (tB + 2) & 31;                                \
    /* ---- U(A) loads: contiguous 1KB each, fly until PV(A) ---- */                   \
    bf16x8 ufA[6][2];                                                                  \
    _Pragma("unroll") for (int tc = 0; tc < 6; ++tc) {                                 \
      const ushort_t* up = Ug + (size_t)tA * 24576 + tc * 1024;                        \
      ufA[tc][0] = *(const bf16x8*)(up);                                               \
      ufA[tc][1] = *(const bf16x8*)(up + 32);                                          \
    }                                                                                  \
    /* ---- SM(A); then reload kfA in place for next iteration ---- */                 \
    uint_t pwA[4][2];                                                                  \
    SM_PHASE(pwA, kfA0, kfA1)                                                          \
    PS_WRITE(CUR, 0, pwA)                                                              \
    kfA0 = *(const bf16x8*)(Kg + (size_t)tA2 * 4096);                                  \
    kfA1 = *(const bf16x8*)(Kg + (size_t)tA2 * 4096 + 32);                             \
    /* ---- SM(B); reload kfB ---- */                                                  \
    uint_t pwB[4][2];                                                                  \
    SM_PHASE(pwB, kfB0, kfB1)                                                          \
    PS_WRITE(CUR, 1, pwB)                                                              \
    kfB0 = *(const bf16x8*)(Kg + (size_t)tB2 * 4096);                                  \
    kfB1 = *(const bf16x8*)(Kg + (size_t)tB2 * 4096 + 32);                             \
    /* ---- single barrier for both subtiles (lgkm only; vmem in flight) ---- */       \
    LGKM_BARRIER()                                                                     \
    /* ---- PV(A), with ufB[tc] loaded as ufA[tc] dies (live U stays 48 reg) ---- */   \
    bf16x8 pA[4][2];                                                                   \
    PA_READ(pA, CUR, 0)                                                                \
    bf16x8 ufB[6][2];                                                                  \
    _Pragma("unroll") for (int tc = 0; tc < 6; ++tc) {                                 \
      _Pragma("unroll") for (int ti = 0; ti < 4; ++ti)                                 \
          acc[ti][tc] = MFMA16(pA[ti][0], ufA[tc][0], acc[ti][tc]);                    \
      _Pragma("unroll") for (int ti = 0; ti < 4; ++ti)                                 \
          acc[ti][tc] = MFMA16(pA[ti][1], ufA[tc][1], acc[ti][tc]);                    \
      const ushort_t* up = Ug + (size_t)tB * 24576 + tc * 1024;                        \
      ufB[tc][0] = *(const bf16x8*)(up);                                               \
      ufB[tc][1] = *(const bf16x8*)(up + 32);                                          \
    }                                                                                  \
    /* ---- PV(B) ---- */                                                              \
    PA_READ(pA, CUR, 1)                                                                \
    _Pragma("unroll") for (int tc = 0; tc < 6; ++tc) {                                 \
      _Pragma("unroll") for (int ti = 0; ti < 4; ++ti)                                 \
          acc[ti][tc] = MFMA16(pA[ti][0], ufB[tc][0], acc[ti][tc]);                    \
      _Pragma("unroll") for (int ti = 0; ti < 4; ++ti)                                 \
          acc[ti][tc] = MFMA16(pA[ti][1], ufB[tc][1], acc[ti][tc]);                    \
    }                                                                                  \
  }

  for (int jtp = 0; jtp < 16; jtp += 2) {
    ATTN_STEP(jtp, 0)
    ATTN_STEP(jtp + 1, 1)
  }
#undef ATTN_STEP
#undef PA_READ
#undef PS_WRITE
#undef SM_PHASE
#undef LGKM_BARRIER

  // ---- softmax denominators ----
#pragma unroll
  for (int ti = 0; ti < 4; ++ti) {
    lp[ti] += __shfl_xor(lp[ti], 16);
    lp[ti] += __shfl_xor(lp[ti], 32);
  }
  if (lane < 16) {
#pragma unroll
    for (int ti = 0; ti < 4; ++ti) Lw[w][ti * 16 + lane] = lp[ti];
  }
  __syncthreads();
  if (t < 64) Ls[t] = 1.0f / (Lw[0][t] + Lw[1][t] + Lw[2][t] + Lw[3][t]);
  __syncthreads();

  // ---- epilogue: normalize, store bf16 partial O ----
  __hip_bfloat16* Op = Ow + ((size_t)bh * 2048 + i0) * 384 + w * 96 + l16;
#pragma unroll
  for (int ti = 0; ti < 4; ++ti)
#pragma unroll
    for (int r = 0; r < 4; ++r) {
      const float inv = Ls[ti * 16 + quad * 4 + r];
      __hip_bfloat16* op = Op + (size_t)(ti * 16 + quad * 4 + r) * 384;
#pragma unroll
      for (int tc = 0; tc < 6; ++tc) op[tc * 16] = __float2bfloat16(acc[ti][tc][r] * inv);
    }
}

// ---------- reduce 8 heads ----------
__global__ __launch_bounds__(256) void reduce_kernel(const uint_t* __restrict__ OwU,
                                                     float2* __restrict__ out) {
  const int idx = blockIdx.x * 256 + threadIdx.x;
  const int b = idx / 393216;
  const int rem = idx - b * 393216;
  const uint_t* p = OwU + (size_t)b * 8 * 393216 + rem;
  float s0 = 0.f, s1 = 0.f;
#pragma unroll
  for (int h = 0; h < 8; ++h) {
    const uint_t v = p[(size_t)h * 393216];
    s0 += __uint_as_float(v << 16);
    s1 += __uint_as_float(v & 0xffff0000u);
  }
  out[(size_t)b * 393216 + rem] = float2{s0, s1};
}

extern "C" void kernel_launch(void* const* d_in, const int* in_sizes, int n_in,
                              void* d_out, int out_size, void* d_ws, size_t ws_size,
                              hipStream_t stream) {
  const float* X  = (const float*)d_in[0];
  const float* Wq = (const float*)d_in[1];
  const float* Wk = (const float*)d_in[2];
  const float* Wv = (const float*)d_in[3];
  const float* Wr = (const float*)d_in[4];

  char* ws = (char*)d_ws;
  ushort_t* Mw  = (ushort_t*)(ws);
  ushort_t* Qw  = (ushort_t*)(ws + 2359296);
  ushort_t* Kw  = (ushort_t*)(ws + 10747904);
  ushort_t* UT  = (ushort_t*)(ws + 19136512);
  __hip_bfloat16* Ow = (__hip_bfloat16*)(ws + 69468160);
  ushort_t* Xw  = (ushort_t*)(ws + 69468160);   // aliases Ow (dead until attn)
  ushort_t* Wqw = (ushort_t*)(ws + 75759616);   // aliases Ow
  ushort_t* Wkw = (ushort_t*)(ws + 76054528);   // aliases Ow

  hipMemsetAsync(ws + 2359296, 0, 16777216, stream);  // dq 48->64 pad of Q/K

  cvt_kernel<<<dim3(3072), 256, 0, stream>>>(X, Xw, 786432);
  cvt_kernel<<<dim3(144), 256, 0, stream>>>(Wq, Wqw, 36864);
  cvt_kernel<<<dim3(144), 256, 0, stream>>>(Wk, Wkw, 36864);
  prep_m_kernel<<<dim3(6, 6, 8), 256, 0, stream>>>(Wr, Wv, Mw);

  gemm_kernel<0><<<dim3(64, 3), 256, 0, stream>>>(Xw, Wqw, Qw);
  gemm_kernel<0><<<dim3(64, 3), 256, 0, stream>>>(Xw, Wkw, Kw);
  gemm_kernel<1><<<dim3(3, 16, 32), 256, 0, stream>>>(Mw, Xw, UT);

  attn_pv_kernel<<<dim3(1024), 256, 0, stream>>>(Qw, Kw, UT, Ow);
  reduce_kernel<<<dim3(6144), 256, 0, stream>>>((const uint_t*)Ow, (float2*)d_out);
}

// Round 8
// 314.803 us; speedup vs baseline: 1.3570x; 1.3570x over previous
//
#include <hip/hip_runtime.h>
#include <hip/hip_bf16.h>

// B=4, N=2048, DIMX=384, DIMQ=48, H=8.
// out_b = sum_h softmax(Q K^T/sqrt(48)) @ U_bh,  U_bh = X_b M_h^T,  M_h = W_rh W_vh.
// ws layout (bytes), with Xw/Wqw/Wkw aliased INSIDE Ow (dead until attn runs):
//   Mw  bf16 [h*384+c][k:384]          @ 0           (2,359,296)
//   Qw  bf16 [bh][i:2048][d:64 pad]    @ 2,359,296   (8,388,608)
//   Kw  bf16 same                      @ 10,747,904  (8,388,608)
//   UT  bf16 [bh][jt:32][swz(c,j:64)]  @ 19,136,512  (50,331,648)  (tiled + XOR-swizzled)
//   Ow  bf16 [bh][i:2048][c:384]       @ 69,468,160  (50,331,648)
//     Xw  bf16 [b][j:2048][k:384]      @ 69,468,160  (6,291,456)   } alias Ow
//     Wqw bf16 [384][384]              @ 75,759,616  (294,912)     }
//     Wkw bf16 [384][384]              @ 76,054,528  (294,912)     }
// peak = 119,799,808 B
//
// ROUND-12: attn is CACHE-BANDWIDTH bound (L2/L3), incl. 2x line over-fetch from the
// 128B-lane-stride fragment loads (16 lines touched, 64B used). Evidence: wall scales
// with U re-read traffic (R4: 2x blocks -> 2x dur) and with nothing else (R1 latency,
// R3/R4 occupancy, R6 layout, R7 barriers all null). Fix: (1) i-tile 128 (8-wave
// 512-thread blocks, 16 blocks/bh) halves U re-reads; (2) U(jt) tile staged in LDS
// once per block via global_load_lds width=16 (contiguous, zero over-fetch), waves
// ds_read fragments (XOR-swizzled, 2-way banks; swizzle baked into UT by gemm<1>).
// Net cache traffic ~3 GB -> ~0.8 GB per dispatch.

typedef short bf16x8 __attribute__((ext_vector_type(8)));
typedef float f32x4 __attribute__((ext_vector_type(4)));
typedef unsigned short ushort_t;
typedef unsigned int uint_t;

#define MFMA16(A, B, C) __builtin_amdgcn_mfma_f32_16x16x32_bf16(A, B, C, 0, 0, 0)

__device__ __forceinline__ ushort_t bits_bf16(float a) {
  __hip_bfloat16 h = __float2bfloat16(a);
  return *reinterpret_cast<ushort_t*>(&h);
}

// ---------- fp32 -> bf16 convert ----------
__global__ __launch_bounds__(256) void cvt_kernel(const float* __restrict__ src,
                                                  ushort_t* __restrict__ dst, int n4) {
  const int idx = blockIdx.x * 256 + threadIdx.x;
  if (idx >= n4) return;
  const float4 v = ((const float4*)src)[idx];
  ushort4 o;
  o.x = bits_bf16(v.x); o.y = bits_bf16(v.y); o.z = bits_bf16(v.z); o.w = bits_bf16(v.w);
  ((ushort4*)dst)[idx] = o;
}

// ---------- M_h = W_rh * W_vh  (fp32 compute, bf16 out; tiny) ----------
__global__ __launch_bounds__(256) void prep_m_kernel(const float* __restrict__ Wr,
                                                     const float* __restrict__ Wv,
                                                     ushort_t* __restrict__ Mw) {
  __shared__ float As[32][68];
  __shared__ float Bs[32][68];
  const int t = threadIdx.x;
  const int d0 = blockIdx.x << 6;
  const int k0 = blockIdx.y << 6;
  const int h  = blockIdx.z;
  const int ty = t >> 4, tx = t & 15;
  float acc[4][4] = {};
  for (int x0 = 0; x0 < 384; x0 += 32) {
#pragma unroll
    for (int rep = 0; rep < 2; ++rep) {
      int idx = t + (rep << 8);
      int row = idx >> 3, kq = (idx & 7) << 2;
      const float4 a = *(const float4*)&Wr[(size_t)(d0 + row) * 3072 + h * 384 + x0 + kq];
      As[kq + 0][row] = a.x; As[kq + 1][row] = a.y; As[kq + 2][row] = a.z; As[kq + 3][row] = a.w;
      int bro = idx >> 4, bc4 = (idx & 15) << 2;
      *(float4*)&Bs[bro][bc4] = *(const float4*)&Wv[(size_t)(h * 384 + x0 + bro) * 384 + k0 + bc4];
    }
    __syncthreads();
#pragma unroll
    for (int kk = 0; kk < 32; ++kk) {
      const float4 av = *(const float4*)&As[kk][ty << 2];
      const float4 bv = *(const float4*)&Bs[kk][tx << 2];
      const float a[4] = {av.x, av.y, av.z, av.w};
      const float b[4] = {bv.x, bv.y, bv.z, bv.w};
#pragma unroll
      for (int r = 0; r < 4; ++r)
#pragma unroll
        for (int c = 0; c < 4; ++c) acc[r][c] = fmaf(a[r], b[c], acc[r][c]);
    }
    __syncthreads();
  }
#pragma unroll
  for (int r = 0; r < 4; ++r)
#pragma unroll
    for (int c = 0; c < 4; ++c)
      Mw[(size_t)(h * 384 + d0 + (ty << 2) + r) * 384 + k0 + (tx << 2) + c] =
          bits_bf16(acc[r][c]);
}

// ---------- unified bf16 MFMA GEMM ----------
// MODE 0: dst = Q/K packed [bh][i][64-pad]. MODE 1: dst = UT tiled+swizzled:
//   element index within 48KB tile = (c*64 + jo) ^ ((c&7)<<3)  [byte ^ ((c&7)<<4)]
template <int MODE>
__global__ __launch_bounds__(256) void gemm_kernel(const ushort_t* __restrict__ Aall,
                                                   const ushort_t* __restrict__ Ball,
                                                   ushort_t* __restrict__ dst) {
  __shared__ ushort_t As[128 * 40];
  __shared__ ushort_t Bs[128 * 40];
  const int t = threadIdx.x;
  const int w = t >> 6, lane = t & 63, quad = lane >> 4, l16 = lane & 15;
  const int m0 = blockIdx.x << 7;
  const int n0 = blockIdx.y << 7;
  const ushort_t* Ap;
  const ushort_t* Bp;
  if (MODE == 0) {
    Ap = Aall; Bp = Ball;
  } else {
    const int bh = blockIdx.z, h = bh & 7, b = bh >> 3;
    Ap = Aall + (size_t)h * 384 * 384;
    Bp = Ball + (size_t)b * 2048 * 384;
  }
  const int wm = (w & 1) << 6, wn = (w >> 1) << 6;
  f32x4 acc[4][4] = {};

  for (int k0 = 0; k0 < 384; k0 += 32) {
    __syncthreads();
#pragma unroll
    for (int rep = 0; rep < 2; ++rep) {
      const int idx = t + (rep << 8);
      const int row = idx >> 2, c8 = (idx & 3) << 3;
      *(bf16x8*)&As[row * 40 + c8] = *(const bf16x8*)&Ap[(size_t)(m0 + row) * 384 + k0 + c8];
      *(bf16x8*)&Bs[row * 40 + c8] = *(const bf16x8*)&Bp[(size_t)(n0 + row) * 384 + k0 + c8];
    }
    __syncthreads();
    bf16x8 af[4], bfr[4];
#pragma unroll
    for (int x = 0; x < 4; ++x) {
      af[x] = *(const bf16x8*)&As[(wm + x * 16 + l16) * 40 + quad * 8];
      bfr[x] = *(const bf16x8*)&Bs[(wn + x * 16 + l16) * 40 + quad * 8];
    }
#pragma unroll
    for (int ti = 0; ti < 4; ++ti)
#pragma unroll
      for (int tj = 0; tj < 4; ++tj)
        acc[ti][tj] = MFMA16(af[ti], bfr[tj], acc[ti][tj]);
  }

#pragma unroll
  for (int ti = 0; ti < 4; ++ti) {
    const int gm0 = m0 + wm + ti * 16 + quad * 4;
#pragma unroll
    for (int tj = 0; tj < 4; ++tj) {
      const int gn = n0 + wn + tj * 16 + l16;
#pragma unroll
      for (int r = 0; r < 4; ++r) {
        const ushort_t v = bits_bf16(acc[ti][tj][r]);
        if (MODE == 0) {
          const int m = gm0 + r, b = m >> 11, i = m & 2047;
          const int h = gn / 48, dd = gn - h * 48;
          dst[(size_t)(((b << 3) + h) * 2048 + i) * 64 + dd] = v;
        } else {
          const int jt = gn >> 6, jo = gn & 63;
          const int c = gm0 + r;
          const int swz = ((c << 6) + jo) ^ ((c & 7) << 3);
          dst[(size_t)blockIdx.z * 786432 + (size_t)jt * 24576 + swz] = v;
        }
      }
    }
  }
}

// ---------- fused attention: 8-wave / 128-i block, LDS-staged U ----------
// Wave roles: scores: (ih = w>>2, js = w&3) -> i-half x 16-j strip.
//             PV:     (ih = w>>2, cs = w&3) -> i-half x 96-c strip.
// Per jt: [scores->exp->Ps write] BARRIER(vmcnt0+lgkm0) [K(jt+1), stage U(jt+1)
// via global_load_lds (contiguous 48KB), pA reads, PV from LDS U(jt)].
// Staged loads get a near-full-iteration flight before the next barrier's drain.
__global__ __launch_bounds__(512) void attn_pv_kernel(const ushort_t* __restrict__ Qw,
                                                      const ushort_t* __restrict__ Kw,
                                                      const ushort_t* __restrict__ UT,
                                                      __hip_bfloat16* __restrict__ Ow) {
  __shared__ ushort_t Us[2][24576];     // 2 x 48KB U tile (swizzled content, linear copy)
  __shared__ uint_t Ps[2][128 * 44];    // 45 KB
  __shared__ float Lw[4][128];
  __shared__ float Ls[128];

  const int t = threadIdx.x;
  const int w = t >> 6, lane = t & 63, quad = lane >> 4, l16 = lane & 15;
  const int js = w & 3, ih = w >> 2;    // js also serves as cs for PV
  const int bid = blockIdx.x;
  const int h = bid & 7, i0 = ((bid >> 3) & 15) << 7, b = bid >> 7;
  const int bh = (b << 3) + h;

  const ushort_t* Qg = Qw + ((size_t)bh * 2048 + i0 + ih * 64 + l16) * 64 + quad * 8;
  const ushort_t* Kg = Kw + ((size_t)bh * 2048 + js * 16 + l16) * 64 + quad * 8;
  const ushort_t* Ut = UT + (size_t)bh * 786432;

  bf16x8 qf[4][2];
#pragma unroll
  for (int ti = 0; ti < 4; ++ti)
#pragma unroll
    for (int kh = 0; kh < 2; ++kh)
      qf[ti][kh] = *(const bf16x8*)(Qg + (size_t)ti * 16 * 64 + kh * 32);

  f32x4 acc[4][6] = {};
  float lp[4] = {0.f, 0.f, 0.f, 0.f};
  // exp(s/sqrt(48)) = exp2(s * log2(e)/sqrt(48))
  const float c_exp = 0.14433756729740643f * 1.4426950408889634f;

  // per-lane swizzled LDS byte offsets for the 12 uf reads (tc x ks), cs = js
  // byte = c*128 + ks*64 + quad*16, swz ^= (l16&7)<<4, c = js*96 + tc*16 + l16
  const int usw = (l16 & 7) << 4;

#define STAGE_U(BUF, JT)                                                               \
  {                                                                                    \
    const ushort_t* gs = Ut + (size_t)(JT) * 24576 + (w << 9) + (lane << 3);           \
    ushort_t* ls = &Us[BUF][(w << 9)];                                                 \
    _Pragma("unroll") for (int r2 = 0; r2 < 6; ++r2)                                   \
        __builtin_amdgcn_global_load_lds(                                              \
            (const __attribute__((address_space(1))) void*)(gs + (r2 << 12)),          \
            (__attribute__((address_space(3))) void*)(ls + (r2 << 12)), 16, 0, 0);     \
  }

  // prologue: K(0) fragments + stage U(0) -> Us[0]
  bf16x8 kf0 = *(const bf16x8*)(Kg);
  bf16x8 kf1 = *(const bf16x8*)(Kg + 32);
  STAGE_U(0, 0)

  int pb = 0;
  for (int jt = 0; jt < 32; ++jt) {
    // ---- scores(jt): S^T for (i-half ih, j-strip js) ----
    uint_t pw[4][2];
#pragma unroll
    for (int ti = 0; ti < 4; ++ti) {
      f32x4 z = {0.f, 0.f, 0.f, 0.f};
      z = MFMA16(kf0, qf[ti][0], z);
      z = MFMA16(kf1, qf[ti][1], z);
      const uint_t r0 = __float_as_uint(__builtin_amdgcn_exp2f(z[0] * c_exp)) + 0x8000u;
      const uint_t r1 = __float_as_uint(__builtin_amdgcn_exp2f(z[1] * c_exp)) + 0x8000u;
      const uint_t r2 = __float_as_uint(__builtin_amdgcn_exp2f(z[2] * c_exp)) + 0x8000u;
      const uint_t r3 = __float_as_uint(__builtin_amdgcn_exp2f(z[3] * c_exp)) + 0x8000u;
      const uint_t p0 = __builtin_amdgcn_perm(r1, r0, 0x07060302u);
      const uint_t p1 = __builtin_amdgcn_perm(r3, r2, 0x07060302u);
      pw[ti][0] = p0;
      pw[ti][1] = p1;
      // l from the STORED (rounded) values so normalization is exact
      lp[ti] += (__uint_as_float(p0 << 16) + __uint_as_float(p0 & 0xffff0000u)) +
                (__uint_as_float(p1 << 16) + __uint_as_float(p1 & 0xffff0000u));
    }
    // ---- write Ps[pb]: rows ih*64 + ti*16 + l16, words js*8 + quad*2 ----
    {
      uint2* p = (uint2*)&Ps[pb][(ih * 64) * 44 + js * 8 + quad * 2];
#pragma unroll
      for (int ti = 0; ti < 4; ++ti)
        *(uint2*)((uint_t*)p + (ti * 16 + l16) * 44) = uint2{pw[ti][0], pw[ti][1]};
    }
    // ---- barrier: Ps visible; U(jt) stage drained (flight ~= full prev iteration) ----
    __builtin_amdgcn_sched_barrier(0);
    asm volatile("s_waitcnt vmcnt(0) lgkmcnt(0)");
    __builtin_amdgcn_s_barrier();
    __builtin_amdgcn_sched_barrier(0);
    // ---- post-barrier: K(jt+1) frags, stage U(jt+1), then PV(jt) from LDS ----
    {
      const int jn = ((jt + 1) & 31);
      kf0 = *(const bf16x8*)(Kg + (size_t)jn * 4096);
      kf1 = *(const bf16x8*)(Kg + (size_t)jn * 4096 + 32);
      STAGE_U(jn & 1, jn)
    }
    // P A-fragments (2-way banks at stride 44)
    bf16x8 pA[4][2];
#pragma unroll
    for (int ti = 0; ti < 4; ++ti)
#pragma unroll
      for (int ks = 0; ks < 2; ++ks)
        pA[ti][ks] = *(const bf16x8*)&Ps[pb][(ih * 64 + ti * 16 + l16) * 44 +
                                             ks * 16 + quad * 4];
    // PV: U fragments from LDS (swizzled; 2-way banks per quad-phase)
    const char* Ub = (const char*)Us[jt & 1];
#pragma unroll
    for (int tc = 0; tc < 6; ++tc) {
      const int c = js * 96 + tc * 16 + l16;
      const int b0 = (c << 7) + (quad << 4);
      const bf16x8 u0 = *(const bf16x8*)(Ub + (b0 ^ usw));
      const bf16x8 u1 = *(const bf16x8*)(Ub + ((b0 + 64) ^ usw));
#pragma unroll
      for (int ti = 0; ti < 4; ++ti) acc[ti][tc] = MFMA16(pA[ti][0], u0, acc[ti][tc]);
#pragma unroll
      for (int ti = 0; ti < 4; ++ti) acc[ti][tc] = MFMA16(pA[ti][1], u1, acc[ti][tc]);
    }
    pb ^= 1;
  }
#undef STAGE_U

  // ---- softmax denominators: reduce over quads, then over the 4 j-strip waves ----
#pragma unroll
  for (int ti = 0; ti < 4; ++ti) {
    lp[ti] += __shfl_xor(lp[ti], 16);
    lp[ti] += __shfl_xor(lp[ti], 32);
  }
  if (lane < 16) {
#pragma unroll
    for (int ti = 0; ti < 4; ++ti) Lw[js][ih * 64 + ti * 16 + lane] = lp[ti];
  }
  __syncthreads();
  if (t < 128) Ls[t] = 1.0f / (Lw[0][t] + Lw[1][t] + Lw[2][t] + Lw[3][t]);
  __syncthreads();

  // ---- epilogue: normalize, store bf16 partial O ----
  __hip_bfloat16* Op = Ow + ((size_t)bh * 2048 + i0 + ih * 64) * 384 + js * 96 + l16;
#pragma unroll
  for (int ti = 0; ti < 4; ++ti)
#pragma unroll
    for (int r = 0; r < 4; ++r) {
      const float inv = Ls[ih * 64 + ti * 16 + quad * 4 + r];
      __hip_bfloat16* op = Op + (size_t)(ti * 16 + quad * 4 + r) * 384;
#pragma unroll
      for (int tc = 0; tc < 6; ++tc) op[tc * 16] = __float2bfloat16(acc[ti][tc][r] * inv);
    }
}

// ---------- reduce 8 heads ----------
__global__ __launch_bounds__(256) void reduce_kernel(const uint_t* __restrict__ OwU,
                                                     float2* __restrict__ out) {
  const int idx = blockIdx.x * 256 + threadIdx.x;
  const int b = idx / 393216;
  const int rem = idx - b * 393216;
  const uint_t* p = OwU + (size_t)b * 8 * 393216 + rem;
  float s0 = 0.f, s1 = 0.f;
#pragma unroll
  for (int h = 0; h < 8; ++h) {
    const uint_t v = p[(size_t)h * 393216];
    s0 += __uint_as_float(v << 16);
    s1 += __uint_as_float(v & 0xffff0000u);
  }
  out[(size_t)b * 393216 + rem] = float2{s0, s1};
}

extern "C" void kernel_launch(void* const* d_in, const int* in_sizes, int n_in,
                              void* d_out, int out_size, void* d_ws, size_t ws_size,
                              hipStream_t stream) {
  const float* X  = (const float*)d_in[0];
  const float* Wq = (const float*)d_in[1];
  const float* Wk = (const float*)d_in[2];
  const float* Wv = (const float*)d_in[3];
  const float* Wr = (const float*)d_in[4];

  char* ws = (char*)d_ws;
  ushort_t* Mw  = (ushort_t*)(ws);
  ushort_t* Qw  = (ushort_t*)(ws + 2359296);
  ushort_t* Kw  = (ushort_t*)(ws + 10747904);
  ushort_t* UT  = (ushort_t*)(ws + 19136512);
  __hip_bfloat16* Ow = (__hip_bfloat16*)(ws + 69468160);
  ushort_t* Xw  = (ushort_t*)(ws + 69468160);   // aliases Ow (dead until attn)
  ushort_t* Wqw = (ushort_t*)(ws + 75759616);   // aliases Ow
  ushort_t* Wkw = (ushort_t*)(ws + 76054528);   // aliases Ow

  hipMemsetAsync(ws + 2359296, 0, 16777216, stream);  // dq 48->64 pad of Q/K

  cvt_kernel<<<dim3(3072), 256, 0, stream>>>(X, Xw, 786432);
  cvt_kernel<<<dim3(144), 256, 0, stream>>>(Wq, Wqw, 36864);
  cvt_kernel<<<dim3(144), 256, 0, stream>>>(Wk, Wkw, 36864);
  prep_m_kernel<<<dim3(6, 6, 8), 256, 0, stream>>>(Wr, Wv, Mw);

  gemm_kernel<0><<<dim3(64, 3), 256, 0, stream>>>(Xw, Wqw, Qw);
  gemm_kernel<0><<<dim3(64, 3), 256, 0, stream>>>(Xw, Wkw, Kw);
  gemm_kernel<1><<<dim3(3, 16, 32), 256, 0, stream>>>(Mw, Xw, UT);

  attn_pv_kernel<<<dim3(512), 512, 0, stream>>>(Qw, Kw, UT, Ow);
  reduce_kernel<<<dim3(6144), 256, 0, stream>>>((const uint_t*)Ow, (float2*)d_out);
}

// Round 9
// 310.050 us; speedup vs baseline: 1.3778x; 1.0153x over previous
//
#include <hip/hip_runtime.h>
#include <hip/hip_bf16.h>

// B=4, N=2048, DIMX=384, DIMQ=48, H=8.
// out_b = sum_h softmax(Q K^T/sqrt(48)) @ U_bh,  U_bh = X_b M_h^T,  M_h = W_rh W_vh.
// ws layout (bytes), with Xw/Wqw/Wkw aliased INSIDE Ow (dead until attn runs):
//   Mw  bf16 [h*384+c][k:384]          @ 0           (2,359,296)
//   Qw  bf16 [bh][i:2048][d:64 pad]    @ 2,359,296   (8,388,608)
//   Kw  bf16 same                      @ 10,747,904  (8,388,608)
//   UT  bf16 [bh][jt:32][swz(c,j:64)]  @ 19,136,512  (50,331,648)  (tiled + XOR-swizzled)
//   Ow  bf16 [bh][i:2048][c:384]       @ 69,468,160  (50,331,648)
//     Xw  bf16 [b][j:2048][k:384]      @ 69,468,160  (6,291,456)   } alias Ow
//     Wqw bf16 [384][384]              @ 75,759,616  (294,912)     }
//     Wkw bf16 [384][384]              @ 76,054,528  (294,912)     }
// peak = 119,799,808 B
//
// R8 (WIN, 233->155us attn): cache-BW theory confirmed -- U staged in LDS via
// global_load_lds (zero over-fetch), 8-wave/128-i blocks halve U re-reads.
// ROUND-13: un-serialize SM from PV (R2's overlap, now register-affordable since
// U left the register file): per iteration, post-barrier region computes
// {pA reads, stage U(jt+1), scores(jt+1), exp/pack, Ps[nxt] write, K(jt+2)
// prefetch, PV(jt)} -- all mutually independent, ONE barrier at region end.
// MFMA stream 56-deep, exp chain hides under PV. Live regs ~200 (R0-proven).

typedef short bf16x8 __attribute__((ext_vector_type(8)));
typedef float f32x4 __attribute__((ext_vector_type(4)));
typedef unsigned short ushort_t;
typedef unsigned int uint_t;

#define MFMA16(A, B, C) __builtin_amdgcn_mfma_f32_16x16x32_bf16(A, B, C, 0, 0, 0)

__device__ __forceinline__ ushort_t bits_bf16(float a) {
  __hip_bfloat16 h = __float2bfloat16(a);
  return *reinterpret_cast<ushort_t*>(&h);
}

// ---------- fp32 -> bf16 convert ----------
__global__ __launch_bounds__(256) void cvt_kernel(const float* __restrict__ src,
                                                  ushort_t* __restrict__ dst, int n4) {
  const int idx = blockIdx.x * 256 + threadIdx.x;
  if (idx >= n4) return;
  const float4 v = ((const float4*)src)[idx];
  ushort4 o;
  o.x = bits_bf16(v.x); o.y = bits_bf16(v.y); o.z = bits_bf16(v.z); o.w = bits_bf16(v.w);
  ((ushort4*)dst)[idx] = o;
}

// ---------- M_h = W_rh * W_vh  (fp32 compute, bf16 out; tiny) ----------
__global__ __launch_bounds__(256) void prep_m_kernel(const float* __restrict__ Wr,
                                                     const float* __restrict__ Wv,
                                                     ushort_t* __restrict__ Mw) {
  __shared__ float As[32][68];
  __shared__ float Bs[32][68];
  const int t = threadIdx.x;
  const int d0 = blockIdx.x << 6;
  const int k0 = blockIdx.y << 6;
  const int h  = blockIdx.z;
  const int ty = t >> 4, tx = t & 15;
  float acc[4][4] = {};
  for (int x0 = 0; x0 < 384; x0 += 32) {
#pragma unroll
    for (int rep = 0; rep < 2; ++rep) {
      int idx = t + (rep << 8);
      int row = idx >> 3, kq = (idx & 7) << 2;
      const float4 a = *(const float4*)&Wr[(size_t)(d0 + row) * 3072 + h * 384 + x0 + kq];
      As[kq + 0][row] = a.x; As[kq + 1][row] = a.y; As[kq + 2][row] = a.z; As[kq + 3][row] = a.w;
      int bro = idx >> 4, bc4 = (idx & 15) << 2;
      *(float4*)&Bs[bro][bc4] = *(const float4*)&Wv[(size_t)(h * 384 + x0 + bro) * 384 + k0 + bc4];
    }
    __syncthreads();
#pragma unroll
    for (int kk = 0; kk < 32; ++kk) {
      const float4 av = *(const float4*)&As[kk][ty << 2];
      const float4 bv = *(const float4*)&Bs[kk][tx << 2];
      const float a[4] = {av.x, av.y, av.z, av.w};
      const float b[4] = {bv.x, bv.y, bv.z, bv.w};
#pragma unroll
      for (int r = 0; r < 4; ++r)
#pragma unroll
        for (int c = 0; c < 4; ++c) acc[r][c] = fmaf(a[r], b[c], acc[r][c]);
    }
    __syncthreads();
  }
#pragma unroll
  for (int r = 0; r < 4; ++r)
#pragma unroll
    for (int c = 0; c < 4; ++c)
      Mw[(size_t)(h * 384 + d0 + (ty << 2) + r) * 384 + k0 + (tx << 2) + c] =
          bits_bf16(acc[r][c]);
}

// ---------- unified bf16 MFMA GEMM ----------
// MODE 0: dst = Q/K packed [bh][i][64-pad]. MODE 1: dst = UT tiled+swizzled:
//   element index within 48KB tile = (c*64 + jo) ^ ((c&7)<<3)  [byte ^ ((c&7)<<4)]
template <int MODE>
__global__ __launch_bounds__(256) void gemm_kernel(const ushort_t* __restrict__ Aall,
                                                   const ushort_t* __restrict__ Ball,
                                                   ushort_t* __restrict__ dst) {
  __shared__ ushort_t As[128 * 40];
  __shared__ ushort_t Bs[128 * 40];
  const int t = threadIdx.x;
  const int w = t >> 6, lane = t & 63, quad = lane >> 4, l16 = lane & 15;
  const int m0 = blockIdx.x << 7;
  const int n0 = blockIdx.y << 7;
  const ushort_t* Ap;
  const ushort_t* Bp;
  if (MODE == 0) {
    Ap = Aall; Bp = Ball;
  } else {
    const int bh = blockIdx.z, h = bh & 7, b = bh >> 3;
    Ap = Aall + (size_t)h * 384 * 384;
    Bp = Ball + (size_t)b * 2048 * 384;
  }
  const int wm = (w & 1) << 6, wn = (w >> 1) << 6;
  f32x4 acc[4][4] = {};

  for (int k0 = 0; k0 < 384; k0 += 32) {
    __syncthreads();
#pragma unroll
    for (int rep = 0; rep < 2; ++rep) {
      const int idx = t + (rep << 8);
      const int row = idx >> 2, c8 = (idx & 3) << 3;
      *(bf16x8*)&As[row * 40 + c8] = *(const bf16x8*)&Ap[(size_t)(m0 + row) * 384 + k0 + c8];
      *(bf16x8*)&Bs[row * 40 + c8] = *(const bf16x8*)&Bp[(size_t)(n0 + row) * 384 + k0 + c8];
    }
    __syncthreads();
    bf16x8 af[4], bfr[4];
#pragma unroll
    for (int x = 0; x < 4; ++x) {
      af[x] = *(const bf16x8*)&As[(wm + x * 16 + l16) * 40 + quad * 8];
      bfr[x] = *(const bf16x8*)&Bs[(wn + x * 16 + l16) * 40 + quad * 8];
    }
#pragma unroll
    for (int ti = 0; ti < 4; ++ti)
#pragma unroll
      for (int tj = 0; tj < 4; ++tj)
        acc[ti][tj] = MFMA16(af[ti], bfr[tj], acc[ti][tj]);
  }

#pragma unroll
  for (int ti = 0; ti < 4; ++ti) {
    const int gm0 = m0 + wm + ti * 16 + quad * 4;
#pragma unroll
    for (int tj = 0; tj < 4; ++tj) {
      const int gn = n0 + wn + tj * 16 + l16;
#pragma unroll
      for (int r = 0; r < 4; ++r) {
        const ushort_t v = bits_bf16(acc[ti][tj][r]);
        if (MODE == 0) {
          const int m = gm0 + r, b = m >> 11, i = m & 2047;
          const int h = gn / 48, dd = gn - h * 48;
          dst[(size_t)(((b << 3) + h) * 2048 + i) * 64 + dd] = v;
        } else {
          const int jt = gn >> 6, jo = gn & 63;
          const int c = gm0 + r;
          const int swz = ((c << 6) + jo) ^ ((c & 7) << 3);
          dst[(size_t)blockIdx.z * 786432 + (size_t)jt * 24576 + swz] = v;
        }
      }
    }
  }
}

// ---------- fused attention: 8-wave / 128-i block, LDS-staged U, SM||PV overlap ----
// Wave roles: scores: (ih = w>>2, js = w&3); PV: (ih, cs = w&3).
// Per iteration (one barrier-delimited region): pA reads(Ps[cur]) || stage U(jt+1)
// || scores(jt+1)+exp+Ps[nxt] write || K(jt+2) prefetch || PV(jt) from Us[cur].
// All independent: MFMA stream is 48(PV)+8(SM) deep, exp VALU hides under it.
__global__ __launch_bounds__(512) void attn_pv_kernel(const ushort_t* __restrict__ Qw,
                                                      const ushort_t* __restrict__ Kw,
                                                      const ushort_t* __restrict__ UT,
                                                      __hip_bfloat16* __restrict__ Ow) {
  __shared__ ushort_t Us[2][24576];     // 2 x 48KB U tile (swizzled content)
  __shared__ uint_t Ps[2][128 * 44];    // 45 KB
  __shared__ float Lw[4][128];
  __shared__ float Ls[128];

  const int t = threadIdx.x;
  const int w = t >> 6, lane = t & 63, quad = lane >> 4, l16 = lane & 15;
  const int js = w & 3, ih = w >> 2;
  const int bid = blockIdx.x;
  const int h = bid & 7, i0 = ((bid >> 3) & 15) << 7, b = bid >> 7;
  const int bh = (b << 3) + h;

  const ushort_t* Qg = Qw + ((size_t)bh * 2048 + i0 + ih * 64 + l16) * 64 + quad * 8;
  const ushort_t* Kg = Kw + ((size_t)bh * 2048 + js * 16 + l16) * 64 + quad * 8;
  const ushort_t* Ut = UT + (size_t)bh * 786432;

  bf16x8 qf[4][2];
#pragma unroll
  for (int ti = 0; ti < 4; ++ti)
#pragma unroll
    for (int kh = 0; kh < 2; ++kh)
      qf[ti][kh] = *(const bf16x8*)(Qg + (size_t)ti * 16 * 64 + kh * 32);

  f32x4 acc[4][6] = {};
  float lp[4] = {0.f, 0.f, 0.f, 0.f};
  // exp(s/sqrt(48)) = exp2(s * log2(e)/sqrt(48))
  const float c_exp = 0.14433756729740643f * 1.4426950408889634f;
  const int usw = (l16 & 7) << 4;

#define STAGE_U(BUF, JT)                                                               \
  {                                                                                    \
    const ushort_t* gs = Ut + (size_t)(JT) * 24576 + (w << 9) + (lane << 3);           \
    ushort_t* ls = &Us[BUF][(w << 9)];                                                 \
    _Pragma("unroll") for (int r2 = 0; r2 < 6; ++r2)                                   \
        __builtin_amdgcn_global_load_lds(                                              \
            (const __attribute__((address_space(1))) void*)(gs + (r2 << 12)),          \
            (__attribute__((address_space(3))) void*)(ls + (r2 << 12)), 16, 0, 0);     \
  }

  // scores+exp+pack from K frags (KF0,KF1) -> PW; lp accumulated from stored bits
#define SM_COMPUTE(PW, KF0, KF1)                                                       \
  _Pragma("unroll") for (int ti = 0; ti < 4; ++ti) {                                   \
    f32x4 z = {0.f, 0.f, 0.f, 0.f};                                                    \
    z = MFMA16(KF0, qf[ti][0], z);                                                     \
    z = MFMA16(KF1, qf[ti][1], z);                                                     \
    const uint_t r0 = __float_as_uint(__builtin_amdgcn_exp2f(z[0] * c_exp)) + 0x8000u; \
    const uint_t r1 = __float_as_uint(__builtin_amdgcn_exp2f(z[1] * c_exp)) + 0x8000u; \
    const uint_t r2 = __float_as_uint(__builtin_amdgcn_exp2f(z[2] * c_exp)) + 0x8000u; \
    const uint_t r3 = __float_as_uint(__builtin_amdgcn_exp2f(z[3] * c_exp)) + 0x8000u; \
    const uint_t p0 = __builtin_amdgcn_perm(r1, r0, 0x07060302u);                      \
    const uint_t p1 = __builtin_amdgcn_perm(r3, r2, 0x07060302u);                      \
    PW[ti][0] = p0;                                                                    \
    PW[ti][1] = p1;                                                                    \
    lp[ti] += (__uint_as_float(p0 << 16) + __uint_as_float(p0 & 0xffff0000u)) +        \
              (__uint_as_float(p1 << 16) + __uint_as_float(p1 & 0xffff0000u));         \
  }

#define PS_WRITE(BUF, PW)                                                              \
  {                                                                                    \
    uint2* p = (uint2*)&Ps[BUF][(ih * 64) * 44 + js * 8 + quad * 2];                   \
    _Pragma("unroll") for (int ti = 0; ti < 4; ++ti)                                   \
        *(uint2*)((uint_t*)p + (ti * 16 + l16) * 44) = uint2{PW[ti][0], PW[ti][1]};    \
  }

#define PA_READ(PA, BUF)                                                               \
  _Pragma("unroll") for (int ti = 0; ti < 4; ++ti)                                     \
      _Pragma("unroll") for (int ks = 0; ks < 2; ++ks)                                 \
          PA[ti][ks] = *(const bf16x8*)&Ps[BUF][(ih * 64 + ti * 16 + l16) * 44 +       \
                                                ks * 16 + quad * 4];

#define PV_BODY(PA, BUF)                                                               \
  {                                                                                    \
    const char* Ub = (const char*)Us[BUF];                                             \
    _Pragma("unroll") for (int tc = 0; tc < 6; ++tc) {                                 \
      const int c = js * 96 + tc * 16 + l16;                                           \
      const int b0 = (c << 7) + (quad << 4);                                           \
      const bf16x8 u0 = *(const bf16x8*)(Ub + (b0 ^ usw));                             \
      const bf16x8 u1 = *(const bf16x8*)(Ub + ((b0 + 64) ^ usw));                      \
      _Pragma("unroll") for (int ti = 0; ti < 4; ++ti)                                 \
          acc[ti][tc] = MFMA16(PA[ti][0], u0, acc[ti][tc]);                            \
      _Pragma("unroll") for (int ti = 0; ti < 4; ++ti)                                 \
          acc[ti][tc] = MFMA16(PA[ti][1], u1, acc[ti][tc]);                            \
    }                                                                                  \
  }

#define BARRIER()                                                                      \
  __builtin_amdgcn_sched_barrier(0);                                                   \
  asm volatile("s_waitcnt vmcnt(0) lgkmcnt(0)");                                       \
  __builtin_amdgcn_s_barrier();                                                        \
  __builtin_amdgcn_sched_barrier(0);

  // ---- prologue: stage U(0), SM(0) -> Ps[0], K(1) frags ----
  STAGE_U(0, 0)
  bf16x8 kf0 = *(const bf16x8*)(Kg);
  bf16x8 kf1 = *(const bf16x8*)(Kg + 32);
  {
    uint_t pw[4][2];
    SM_COMPUTE(pw, kf0, kf1)
    PS_WRITE(0, pw)
  }
  kf0 = *(const bf16x8*)(Kg + 4096);
  kf1 = *(const bf16x8*)(Kg + 4096 + 32);
  BARRIER()

  // ---- main loop: iteration jt handles PV(jt) + prepares tile jt+1 ----
  for (int jt = 0; jt < 31; ++jt) {
    const int cur = jt & 1, nxt = cur ^ 1;
    bf16x8 pA[4][2];
    PA_READ(pA, cur)
    STAGE_U(nxt, jt + 1)
    {
      uint_t pw[4][2];
      SM_COMPUTE(pw, kf0, kf1)
      PS_WRITE(nxt, pw)
    }
    {
      const int j2 = (jt + 2) & 31;
      kf0 = *(const bf16x8*)(Kg + (size_t)j2 * 4096);
      kf1 = *(const bf16x8*)(Kg + (size_t)j2 * 4096 + 32);
    }
    PV_BODY(pA, cur)
    BARRIER()
  }
  // ---- final tile 31: PV only ----
  {
    bf16x8 pA[4][2];
    PA_READ(pA, 1)
    PV_BODY(pA, 1)
  }
#undef BARRIER
#undef PV_BODY
#undef PA_READ
#undef PS_WRITE
#undef SM_COMPUTE
#undef STAGE_U

  // ---- softmax denominators: reduce over quads, then over the 4 j-strip waves ----
#pragma unroll
  for (int ti = 0; ti < 4; ++ti) {
    lp[ti] += __shfl_xor(lp[ti], 16);
    lp[ti] += __shfl_xor(lp[ti], 32);
  }
  if (lane < 16) {
#pragma unroll
    for (int ti = 0; ti < 4; ++ti) Lw[js][ih * 64 + ti * 16 + lane] = lp[ti];
  }
  __syncthreads();
  if (t < 128) Ls[t] = 1.0f / (Lw[0][t] + Lw[1][t] + Lw[2][t] + Lw[3][t]);
  __syncthreads();

  // ---- epilogue: normalize, store bf16 partial O ----
  __hip_bfloat16* Op = Ow + ((size_t)bh * 2048 + i0 + ih * 64) * 384 + js * 96 + l16;
#pragma unroll
  for (int ti = 0; ti < 4; ++ti)
#pragma unroll
    for (int r = 0; r < 4; ++r) {
      const float inv = Ls[ih * 64 + ti * 16 + quad * 4 + r];
      __hip_bfloat16* op = Op + (size_t)(ti * 16 + quad * 4 + r) * 384;
#pragma unroll
      for (int tc = 0; tc < 6; ++tc) op[tc * 16] = __float2bfloat16(acc[ti][tc][r] * inv);
    }
}

// ---------- reduce 8 heads ----------
__global__ __launch_bounds__(256) void reduce_kernel(const uint_t* __restrict__ OwU,
                                                     float2* __restrict__ out) {
  const int idx = blockIdx.x * 256 + threadIdx.x;
  const int b = idx / 393216;
  const int rem = idx - b * 393216;
  const uint_t* p = OwU + (size_t)b * 8 * 393216 + rem;
  float s0 = 0.f, s1 = 0.f;
#pragma unroll
  for (int h = 0; h < 8; ++h) {
    const uint_t v = p[(size_t)h * 393216];
    s0 += __uint_as_float(v << 16);
    s1 += __uint_as_float(v & 0xffff0000u);
  }
  out[(size_t)b * 393216 + rem] = float2{s0, s1};
}

extern "C" void kernel_launch(void* const* d_in, const int* in_sizes, int n_in,
                              void* d_out, int out_size, void* d_ws, size_t ws_size,
                              hipStream_t stream) {
  const float* X  = (const float*)d_in[0];
  const float* Wq = (const float*)d_in[1];
  const float* Wk = (const float*)d_in[2];
  const float* Wv = (const float*)d_in[3];
  const float* Wr = (const float*)d_in[4];

  char* ws = (char*)d_ws;
  ushort_t* Mw  = (ushort_t*)(ws);
  ushort_t* Qw  = (ushort_t*)(ws + 2359296);
  ushort_t* Kw  = (ushort_t*)(ws + 10747904);
  ushort_t* UT  = (ushort_t*)(ws + 19136512);
  __hip_bfloat16* Ow = (__hip_bfloat16*)(ws + 69468160);
  ushort_t* Xw  = (ushort_t*)(ws + 69468160);   // aliases Ow (dead until attn)
  ushort_t* Wqw = (ushort_t*)(ws + 75759616);   // aliases Ow
  ushort_t* Wkw = (ushort_t*)(ws + 76054528);   // aliases Ow

  hipMemsetAsync(ws + 2359296, 0, 16777216, stream);  // dq 48->64 pad of Q/K

  cvt_kernel<<<dim3(3072), 256, 0, stream>>>(X, Xw, 786432);
  cvt_kernel<<<dim3(144), 256, 0, stream>>>(Wq, Wqw, 36864);
  cvt_kernel<<<dim3(144), 256, 0, stream>>>(Wk, Wkw, 36864);
  prep_m_kernel<<<dim3(6, 6, 8), 256, 0, stream>>>(Wr, Wv, Mw);

  gemm_kernel<0><<<dim3(64, 3), 256, 0, stream>>>(Xw, Wqw, Qw);
  gemm_kernel<0><<<dim3(64, 3), 256, 0, stream>>>(Xw, Wkw, Kw);
  gemm_kernel<1><<<dim3(3, 16, 32), 256, 0, stream>>>(Mw, Xw, UT);

  attn_pv_kernel<<<dim3(512), 512, 0, stream>>>(Qw, Kw, UT, Ow);
  reduce_kernel<<<dim3(6144), 256, 0, stream>>>((const uint_t*)Ow, (float2*)d_out);
}

// Round 10
// 294.417 us; speedup vs baseline: 1.4509x; 1.0531x over previous
//
#include <hip/hip_runtime.h>
#include <hip/hip_bf16.h>

// B=4, N=2048, DIMX=384, DIMQ=48, H=8.
// out_b = sum_h softmax(Q K^T/sqrt(48)) @ U_bh,  U_bh = X_b M_h^T,  M_h = W_rh W_vh.
// ws layout (bytes), with Xw/Wqw/Wkw aliased INSIDE Ow (dead until attn runs):
//   Mw  bf16 [h*384+c][k:384]          @ 0           (2,359,296)
//   Qw  bf16 [bh][i:2048][d:64 pad]    @ 2,359,296   (8,388,608)
//   Kw  bf16 same                      @ 10,747,904  (8,388,608)   (= Qw + 8,388,608)
//   UT  bf16 [bh][jt:32][swz(c,j:64)]  @ 19,136,512  (50,331,648)  (tiled + XOR-swizzled)
//   Ow  bf16 [bh][i:2048][c:384]       @ 69,468,160  (50,331,648)
//     Xw  bf16 [b][j:2048][k:384]      @ 69,468,160  (6,291,456)   } alias Ow
//     Wqw bf16 [384][384]              @ 75,759,616  (294,912)     } (Wkw = Wqw+294,912)
//     Wkw bf16 [384][384]              @ 76,054,528  (294,912)     }
// peak = 119,799,808 B
//
// R8 (WIN, 233->155us attn): cache-BW bound confirmed; U staged in LDS via
// global_load_lds (zero over-fetch), 8-wave/128-i blocks halve U re-reads.
// R9 (NULL): SM||PV source reorder -- compiler already schedules freely in-region.
// ROUND-14: attn reverted to R8 verbatim. Tail attack: (a) gemm upgraded to the
// m97 pattern (global_load_lds w=16 into linear [128][32] LDS; guide-measured
// 517->874 TF on this exact structure), (b) launch count 10->7: one cvt kernel
// for X/Wq/Wk, one gemm<0> launch for Q AND K (blockIdx.z, adjacent ws buffers).

typedef short bf16x8 __attribute__((ext_vector_type(8)));
typedef float f32x4 __attribute__((ext_vector_type(4)));
typedef unsigned short ushort_t;
typedef unsigned int uint_t;

#define MFMA16(A, B, C) __builtin_amdgcn_mfma_f32_16x16x32_bf16(A, B, C, 0, 0, 0)

__device__ __forceinline__ ushort_t bits_bf16(float a) {
  __hip_bfloat16 h = __float2bfloat16(a);
  return *reinterpret_cast<ushort_t*>(&h);
}

// ---------- fp32 -> bf16 convert: X, Wq, Wk in ONE launch ----------
__global__ __launch_bounds__(256) void cvt_all_kernel(const float* __restrict__ X,
                                                      const float* __restrict__ Wq,
                                                      const float* __restrict__ Wk,
                                                      ushort_t* __restrict__ Xw,
                                                      ushort_t* __restrict__ Wqw,
                                                      ushort_t* __restrict__ Wkw) {
  const int idx = blockIdx.x * 256 + threadIdx.x;
  const float* src;
  ushort_t* dst;
  int off;
  if (idx < 786432) {
    src = X; dst = Xw; off = idx;
  } else if (idx < 786432 + 36864) {
    src = Wq; dst = Wqw; off = idx - 786432;
  } else {
    src = Wk; dst = Wkw; off = idx - (786432 + 36864);
  }
  const float4 v = ((const float4*)src)[off];
  ushort4 o;
  o.x = bits_bf16(v.x); o.y = bits_bf16(v.y); o.z = bits_bf16(v.z); o.w = bits_bf16(v.w);
  ((ushort4*)dst)[off] = o;
}

// ---------- M_h = W_rh * W_vh  (fp32 compute, bf16 out; tiny) ----------
__global__ __launch_bounds__(256) void prep_m_kernel(const float* __restrict__ Wr,
                                                     const float* __restrict__ Wv,
                                                     ushort_t* __restrict__ Mw) {
  __shared__ float As[32][68];
  __shared__ float Bs[32][68];
  const int t = threadIdx.x;
  const int d0 = blockIdx.x << 6;
  const int k0 = blockIdx.y << 6;
  const int h  = blockIdx.z;
  const int ty = t >> 4, tx = t & 15;
  float acc[4][4] = {};
  for (int x0 = 0; x0 < 384; x0 += 32) {
#pragma unroll
    for (int rep = 0; rep < 2; ++rep) {
      int idx = t + (rep << 8);
      int row = idx >> 3, kq = (idx & 7) << 2;
      const float4 a = *(const float4*)&Wr[(size_t)(d0 + row) * 3072 + h * 384 + x0 + kq];
      As[kq + 0][row] = a.x; As[kq + 1][row] = a.y; As[kq + 2][row] = a.z; As[kq + 3][row] = a.w;
      int bro = idx >> 4, bc4 = (idx & 15) << 2;
      *(float4*)&Bs[bro][bc4] = *(const float4*)&Wv[(size_t)(h * 384 + x0 + bro) * 384 + k0 + bc4];
    }
    __syncthreads();
#pragma unroll
    for (int kk = 0; kk < 32; ++kk) {
      const float4 av = *(const float4*)&As[kk][ty << 2];
      const float4 bv = *(const float4*)&Bs[kk][tx << 2];
      const float a[4] = {av.x, av.y, av.z, av.w};
      const float b[4] = {bv.x, bv.y, bv.z, bv.w};
#pragma unroll
      for (int r = 0; r < 4; ++r)
#pragma unroll
        for (int c = 0; c < 4; ++c) acc[r][c] = fmaf(a[r], b[c], acc[r][c]);
    }
    __syncthreads();
  }
#pragma unroll
  for (int r = 0; r < 4; ++r)
#pragma unroll
    for (int c = 0; c < 4; ++c)
      Mw[(size_t)(h * 384 + d0 + (ty << 2) + r) * 384 + k0 + (tx << 2) + c] =
          bits_bf16(acc[r][c]);
}

// ---------- unified bf16 MFMA GEMM, m97 pattern ----------
// Staging: global_load_lds width=16 into LINEAR [128][32]-short LDS (wave-uniform
// base + lane*16: thread t, round r -> lds byte r*4096 + t*16). __syncthreads()
// drains vmcnt (compiler emits vmcnt(0) lgkmcnt(0) before s_barrier).
// MODE 0: A=Xw rows, B=(Wqw|Wkw by blockIdx.z), dst=(Qw|Kw) packed [bh][i][64-pad].
// MODE 1: A=Mw_h, B=Xw_b (bh=blockIdx.z), dst=UT tiled+swizzled:
//   element index within 48KB tile = (c*64 + jo) ^ ((c&7)<<3)
template <int MODE>
__global__ __launch_bounds__(256) void gemm_kernel(const ushort_t* __restrict__ Aall,
                                                   const ushort_t* __restrict__ Ball,
                                                   ushort_t* __restrict__ dst) {
  __shared__ ushort_t As[128 * 32];
  __shared__ ushort_t Bs[128 * 32];
  const int t = threadIdx.x;
  const int w = t >> 6, lane = t & 63, quad = lane >> 4, l16 = lane & 15;
  const int m0 = blockIdx.x << 7;
  const int n0 = blockIdx.y << 7;
  const ushort_t* Ap;
  const ushort_t* Bp;
  if (MODE == 0) {
    Ap = Aall;
    Bp = Ball + (size_t)blockIdx.z * 147456;   // Wqw or Wkw (adjacent)
  } else {
    const int bh = blockIdx.z, h = bh & 7, b = bh >> 3;
    Ap = Aall + (size_t)h * 384 * 384;
    Bp = Ball + (size_t)b * 2048 * 384;
  }
  const int wm = (w & 1) << 6, wn = (w >> 1) << 6;
  const int srow = t >> 2, scol = (t & 3) << 3;   // staging: row t>>2, 8-short chunk
  f32x4 acc[4][4] = {};

  for (int k0 = 0; k0 < 384; k0 += 32) {
    __syncthreads();   // previous compute done before overwrite
#pragma unroll
    for (int r = 0; r < 2; ++r) {
      __builtin_amdgcn_global_load_lds(
          (const __attribute__((address_space(1))) void*)&Ap[(size_t)(m0 + r * 64 + srow) * 384 + k0 + scol],
          (__attribute__((address_space(3))) void*)&As[(r * 64 + srow) * 32 + scol], 16, 0, 0);
      __builtin_amdgcn_global_load_lds(
          (const __attribute__((address_space(1))) void*)&Bp[(size_t)(n0 + r * 64 + srow) * 384 + k0 + scol],
          (__attribute__((address_space(3))) void*)&Bs[(r * 64 + srow) * 32 + scol], 16, 0, 0);
    }
    __syncthreads();   // drains vmcnt(0): staged tiles visible
    bf16x8 af[4], bfr[4];
#pragma unroll
    for (int x = 0; x < 4; ++x) {
      af[x] = *(const bf16x8*)&As[(wm + x * 16 + l16) * 32 + quad * 8];
      bfr[x] = *(const bf16x8*)&Bs[(wn + x * 16 + l16) * 32 + quad * 8];
    }
#pragma unroll
    for (int ti = 0; ti < 4; ++ti)
#pragma unroll
      for (int tj = 0; tj < 4; ++tj)
        acc[ti][tj] = MFMA16(af[ti], bfr[tj], acc[ti][tj]);
  }

#pragma unroll
  for (int ti = 0; ti < 4; ++ti) {
    const int gm0 = m0 + wm + ti * 16 + quad * 4;
#pragma unroll
    for (int tj = 0; tj < 4; ++tj) {
      const int gn = n0 + wn + tj * 16 + l16;
#pragma unroll
      for (int r = 0; r < 4; ++r) {
        const ushort_t v = bits_bf16(acc[ti][tj][r]);
        if (MODE == 0) {
          const int m = gm0 + r, b = m >> 11, i = m & 2047;
          const int h = gn / 48, dd = gn - h * 48;
          dst[(size_t)blockIdx.z * 4194304 +
              (size_t)(((b << 3) + h) * 2048 + i) * 64 + dd] = v;
        } else {
          const int jt = gn >> 6, jo = gn & 63;
          const int c = gm0 + r;
          const int swz = ((c << 6) + jo) ^ ((c & 7) << 3);
          dst[(size_t)blockIdx.z * 786432 + (size_t)jt * 24576 + swz] = v;
        }
      }
    }
  }
}

// ---------- fused attention: 8-wave / 128-i block, LDS-staged U (R8 verbatim) ----
// Wave roles: scores: (ih = w>>2, js = w&3) -> i-half x 16-j strip.
//             PV:     (ih = w>>2, cs = w&3) -> i-half x 96-c strip.
// Per jt: [scores->exp->Ps write] BARRIER(vmcnt0+lgkm0) [K(jt+1), stage U(jt+1)
// via global_load_lds (contiguous 48KB), pA reads, PV from LDS U(jt)].
__global__ __launch_bounds__(512) void attn_pv_kernel(const ushort_t* __restrict__ Qw,
                                                      const ushort_t* __restrict__ Kw,
                                                      const ushort_t* __restrict__ UT,
                                                      __hip_bfloat16* __restrict__ Ow) {
  __shared__ ushort_t Us[2][24576];     // 2 x 48KB U tile (swizzled content, linear copy)
  __shared__ uint_t Ps[2][128 * 44];    // 45 KB
  __shared__ float Lw[4][128];
  __shared__ float Ls[128];

  const int t = threadIdx.x;
  const int w = t >> 6, lane = t & 63, quad = lane >> 4, l16 = lane & 15;
  const int js = w & 3, ih = w >> 2;
  const int bid = blockIdx.x;
  const int h = bid & 7, i0 = ((bid >> 3) & 15) << 7, b = bid >> 7;
  const int bh = (b << 3) + h;

  const ushort_t* Qg = Qw + ((size_t)bh * 2048 + i0 + ih * 64 + l16) * 64 + quad * 8;
  const ushort_t* Kg = Kw + ((size_t)bh * 2048 + js * 16 + l16) * 64 + quad * 8;
  const ushort_t* Ut = UT + (size_t)bh * 786432;

  bf16x8 qf[4][2];
#pragma unroll
  for (int ti = 0; ti < 4; ++ti)
#pragma unroll
    for (int kh = 0; kh < 2; ++kh)
      qf[ti][kh] = *(const bf16x8*)(Qg + (size_t)ti * 16 * 64 + kh * 32);

  f32x4 acc[4][6] = {};
  float lp[4] = {0.f, 0.f, 0.f, 0.f};
  // exp(s/sqrt(48)) = exp2(s * log2(e)/sqrt(48))
  const float c_exp = 0.14433756729740643f * 1.4426950408889634f;
  const int usw = (l16 & 7) << 4;

#define STAGE_U(BUF, JT)                                                               \
  {                                                                                    \
    const ushort_t* gs = Ut + (size_t)(JT) * 24576 + (w << 9) + (lane << 3);           \
    ushort_t* ls = &Us[BUF][(w << 9)];                                                 \
    _Pragma("unroll") for (int r2 = 0; r2 < 6; ++r2)                                   \
        __builtin_amdgcn_global_load_lds(                                              \
            (const __attribute__((address_space(1))) void*)(gs + (r2 << 12)),          \
            (__attribute__((address_space(3))) void*)(ls + (r2 << 12)), 16, 0, 0);     \
  }

  // prologue: K(0) fragments + stage U(0) -> Us[0]
  bf16x8 kf0 = *(const bf16x8*)(Kg);
  bf16x8 kf1 = *(const bf16x8*)(Kg + 32);
  STAGE_U(0, 0)

  int pb = 0;
  for (int jt = 0; jt < 32; ++jt) {
    // ---- scores(jt): S^T for (i-half ih, j-strip js) ----
    uint_t pw[4][2];
#pragma unroll
    for (int ti = 0; ti < 4; ++ti) {
      f32x4 z = {0.f, 0.f, 0.f, 0.f};
      z = MFMA16(kf0, qf[ti][0], z);
      z = MFMA16(kf1, qf[ti][1], z);
      const uint_t r0 = __float_as_uint(__builtin_amdgcn_exp2f(z[0] * c_exp)) + 0x8000u;
      const uint_t r1 = __float_as_uint(__builtin_amdgcn_exp2f(z[1] * c_exp)) + 0x8000u;
      const uint_t r2 = __float_as_uint(__builtin_amdgcn_exp2f(z[2] * c_exp)) + 0x8000u;
      const uint_t r3 = __float_as_uint(__builtin_amdgcn_exp2f(z[3] * c_exp)) + 0x8000u;
      const uint_t p0 = __builtin_amdgcn_perm(r1, r0, 0x07060302u);
      const uint_t p1 = __builtin_amdgcn_perm(r3, r2, 0x07060302u);
      pw[ti][0] = p0;
      pw[ti][1] = p1;
      // l from the STORED (rounded) values so normalization is exact
      lp[ti] += (__uint_as_float(p0 << 16) + __uint_as_float(p0 & 0xffff0000u)) +
                (__uint_as_float(p1 << 16) + __uint_as_float(p1 & 0xffff0000u));
    }
    // ---- write Ps[pb]: rows ih*64 + ti*16 + l16, words js*8 + quad*2 ----
    {
      uint2* p = (uint2*)&Ps[pb][(ih * 64) * 44 + js * 8 + quad * 2];
#pragma unroll
      for (int ti = 0; ti < 4; ++ti)
        *(uint2*)((uint_t*)p + (ti * 16 + l16) * 44) = uint2{pw[ti][0], pw[ti][1]};
    }
    // ---- barrier: Ps visible; U(jt) stage drained (flight ~= full prev iteration) ----
    __builtin_amdgcn_sched_barrier(0);
    asm volatile("s_waitcnt vmcnt(0) lgkmcnt(0)");
    __builtin_amdgcn_s_barrier();
    __builtin_amdgcn_sched_barrier(0);
    // ---- post-barrier: K(jt+1) frags, stage U(jt+1), then PV(jt) from LDS ----
    {
      const int jn = ((jt + 1) & 31);
      kf0 = *(const bf16x8*)(Kg + (size_t)jn * 4096);
      kf1 = *(const bf16x8*)(Kg + (size_t)jn * 4096 + 32);
      STAGE_U(jn & 1, jn)
    }
    // P A-fragments (2-way banks at stride 44)
    bf16x8 pA[4][2];
#pragma unroll
    for (int ti = 0; ti < 4; ++ti)
#pragma unroll
      for (int ks = 0; ks < 2; ++ks)
        pA[ti][ks] = *(const bf16x8*)&Ps[pb][(ih * 64 + ti * 16 + l16) * 44 +
                                             ks * 16 + quad * 4];
    // PV: U fragments from LDS (swizzled; 2-way banks per quad-phase)
    const char* Ub = (const char*)Us[jt & 1];
#pragma unroll
    for (int tc = 0; tc < 6; ++tc) {
      const int c = js * 96 + tc * 16 + l16;
      const int b0 = (c << 7) + (quad << 4);
      const bf16x8 u0 = *(const bf16x8*)(Ub + (b0 ^ usw));
      const bf16x8 u1 = *(const bf16x8*)(Ub + ((b0 + 64) ^ usw));
#pragma unroll
      for (int ti = 0; ti < 4; ++ti) acc[ti][tc] = MFMA16(pA[ti][0], u0, acc[ti][tc]);
#pragma unroll
      for (int ti = 0; ti < 4; ++ti) acc[ti][tc] = MFMA16(pA[ti][1], u1, acc[ti][tc]);
    }
    pb ^= 1;
  }
#undef STAGE_U

  // ---- softmax denominators: reduce over quads, then over the 4 j-strip waves ----
#pragma unroll
  for (int ti = 0; ti < 4; ++ti) {
    lp[ti] += __shfl_xor(lp[ti], 16);
    lp[ti] += __shfl_xor(lp[ti], 32);
  }
  if (lane < 16) {
#pragma unroll
    for (int ti = 0; ti < 4; ++ti) Lw[js][ih * 64 + ti * 16 + lane] = lp[ti];
  }
  __syncthreads();
  if (t < 128) Ls[t] = 1.0f / (Lw[0][t] + Lw[1][t] + Lw[2][t] + Lw[3][t]);
  __syncthreads();

  // ---- epilogue: normalize, store bf16 partial O ----
  __hip_bfloat16* Op = Ow + ((size_t)bh * 2048 + i0 + ih * 64) * 384 + js * 96 + l16;
#pragma unroll
  for (int ti = 0; ti < 4; ++ti)
#pragma unroll
    for (int r = 0; r < 4; ++r) {
      const float inv = Ls[ih * 64 + ti * 16 + quad * 4 + r];
      __hip_bfloat16* op = Op + (size_t)(ti * 16 + quad * 4 + r) * 384;
#pragma unroll
      for (int tc = 0; tc < 6; ++tc) op[tc * 16] = __float2bfloat16(acc[ti][tc][r] * inv);
    }
}

// ---------- reduce 8 heads ----------
__global__ __launch_bounds__(256) void reduce_kernel(const uint_t* __restrict__ OwU,
                                                     float2* __restrict__ out) {
  const int idx = blockIdx.x * 256 + threadIdx.x;
  const int b = idx / 393216;
  const int rem = idx - b * 393216;
  const uint_t* p = OwU + (size_t)b * 8 * 393216 + rem;
  float s0 = 0.f, s1 = 0.f;
#pragma unroll
  for (int h = 0; h < 8; ++h) {
    const uint_t v = p[(size_t)h * 393216];
    s0 += __uint_as_float(v << 16);
    s1 += __uint_as_float(v & 0xffff0000u);
  }
  out[(size_t)b * 393216 + rem] = float2{s0, s1};
}

extern "C" void kernel_launch(void* const* d_in, const int* in_sizes, int n_in,
                              void* d_out, int out_size, void* d_ws, size_t ws_size,
                              hipStream_t stream) {
  const float* X  = (const float*)d_in[0];
  const float* Wq = (const float*)d_in[1];
  const float* Wk = (const float*)d_in[2];
  const float* Wv = (const float*)d_in[3];
  const float* Wr = (const float*)d_in[4];

  char* ws = (char*)d_ws;
  ushort_t* Mw  = (ushort_t*)(ws);
  ushort_t* Qw  = (ushort_t*)(ws + 2359296);     // Kw = Qw + 4,194,304 shorts
  ushort_t* UT  = (ushort_t*)(ws + 19136512);
  __hip_bfloat16* Ow = (__hip_bfloat16*)(ws + 69468160);
  ushort_t* Xw  = (ushort_t*)(ws + 69468160);    // aliases Ow (dead until attn)
  ushort_t* Wqw = (ushort_t*)(ws + 75759616);    // aliases Ow; Wkw = Wqw + 147,456
  ushort_t* Kw  = (ushort_t*)(ws + 10747904);
  ushort_t* Wkw = (ushort_t*)(ws + 76054528);

  hipMemsetAsync(ws + 2359296, 0, 16777216, stream);  // dq 48->64 pad of Q/K

  cvt_all_kernel<<<dim3(3360), 256, 0, stream>>>(X, Wq, Wk, Xw, Wqw, Wkw);
  prep_m_kernel<<<dim3(6, 6, 8), 256, 0, stream>>>(Wr, Wv, Mw);

  gemm_kernel<0><<<dim3(64, 3, 2), 256, 0, stream>>>(Xw, Wqw, Qw);   // z=0:Q, z=1:K
  gemm_kernel<1><<<dim3(3, 16, 32), 256, 0, stream>>>(Mw, Xw, UT);

  attn_pv_kernel<<<dim3(512), 512, 0, stream>>>(Qw, Kw, UT, Ow);
  reduce_kernel<<<dim3(6144), 256, 0, stream>>>((const uint_t*)Ow, (float2*)d_out);
}